// Round 8
// baseline (673.971 us; speedup 1.0000x reference)
//
#include <hip/hip_runtime.h>
#include <math.h>

typedef unsigned short u16;
typedef __attribute__((ext_vector_type(8))) __bf16 bf16x8;
typedef __attribute__((ext_vector_type(4))) float f32x4;

// RNE float -> bf16
__device__ __forceinline__ u16 f2bf(float f) {
  union { float f; unsigned u; } v; v.f = f;
  unsigned u = v.u;
  u += 0x7fffu + ((u >> 16) & 1u);
  return (u16)(u >> 16);
}

// async global->LDS, 16B per lane. LDS dest must be wave-uniform base + lane*16.
__device__ __forceinline__ void glds16(const void* g, void* l) {
  __builtin_amdgcn_global_load_lds((__attribute__((address_space(1))) void*)(g),
                                   (__attribute__((address_space(3))) void*)(l),
                                   16, 0, 0);
}

// ---------------- stage 0: casts / transposes ----------------

__global__ __launch_bounds__(256) void cast_bf16_k(const float* __restrict__ in,
                                                   u16* __restrict__ out, int n4) {
  int i = blockIdx.x * 256 + threadIdx.x;
  if (i < n4) {
    float4 v = ((const float4*)in)[i];
    u16* o = out + (size_t)i * 4;
    o[0] = f2bf(v.x); o[1] = f2bf(v.y); o[2] = f2bf(v.z); o[3] = f2bf(v.w);
  }
}

// out[c*R + r] = bf16(in[r*C + c] * scale)   (R,C multiples of 32)
__global__ __launch_bounds__(256) void transpose_cast(const float* __restrict__ in,
                                                      u16* __restrict__ out,
                                                      int R, int C, float scale) {
  __shared__ float t[32][33];
  int bx = blockIdx.x * 32;  // col block (in)
  int by = blockIdx.y * 32;  // row block (in)
  int tx = threadIdx.x & 31, ty0 = threadIdx.x >> 5;
  for (int ty = ty0; ty < 32; ty += 8)
    t[ty][tx] = in[(size_t)(by + ty) * C + bx + tx];
  __syncthreads();
  for (int ty = ty0; ty < 32; ty += 8)
    out[(size_t)(bx + ty) * R + by + tx] = f2bf(t[tx][ty] * scale);
}

// bias [b][q][k] f32 -> biasF [b][qs:128][ks:128][lane:64][r:4] f32
// (16x16 MFMA C-fragment order: lane=(quad,l16) holds rows quad*4+r, col l16)
__global__ __launch_bounds__(256) void bias_frag(const float* __restrict__ bias,
                                                 float* __restrict__ biasF) {
  int g = blockIdx.x * 256 + threadIdx.x;   // 2*128*128*64 threads
  int lane = g & 63, ks = (g >> 6) & 127, qs = (g >> 13) & 127, b = g >> 20;
  int quad = lane >> 4, l16 = lane & 15;
  int q = qs * 16 + quad * 4, k = ks * 16 + l16;
  const float* ip = bias + ((size_t)(b * 2048 + q)) * 2048 + k;
  float4 o;
  o.x = ip[0];
  o.y = ip[2048];
  o.z = ip[4096];
  o.w = ip[6144];
  ((float4*)biasF)[g] = o;
}

// ---------------- fused Q/K/V projection GEMM, 256x256 tile ----------------
// grid (16, 8, 3); z selects {A, B, output, layout}:
//   z=0: Qh = Xq  * WqT^T -> [b][h][s][64]
//   z=1: Kh = Xkv * WkT^T -> [b][h][s][64]
//   z=2: Vt = Xkv * WvT^T -> [b][h][d][kpos]
// 512 threads = 8 waves (2M x 4N), per-wave C = 128x64, acc[8][4] f32x4.
// BK=64, LDS = 2 buf x (256x64 A + 256x64 B) bf16 = 128 KiB -> 1 block/CU.
//
// Loop follows the catalog-verified MINIMUM 2-PHASE template exactly
// (T3 recipe; round-7's home-grown barrier/vmcnt(8) choreography is
// abandoned after the container failure):
//   prologue: STAGE(0) ; vmcnt(0) ; barrier
//   per tile: STAGE(t+1 -> buf^1)          // flies across compute(t)
//             ds_read buf + setprio(1) MFMAs setprio(0)
//             vmcnt(0) ; barrier ; flip    // ONE barrier per tile
// Race safety (template's own argument): stage(t+1) writes buf^1 only;
// each wave's ds_reads of buf are lgkm-retired before its MFMAs, hence
// before its barrier; vmcnt(0) after compute => stage(t+1) fully landed
// before any wave flips.
// T2 XOR-swizzle (both-sides, rule #21): LDS phys 16B-slot = logical slot
// ^ (row&7), realized as linear glds dest + inverse-swizzled GLOBAL source
// + swizzled ds_read offsets.
__global__ __launch_bounds__(512, 2) void gemm_qkv256(const u16* __restrict__ Xq,
                                                      const u16* __restrict__ Xkv,
                                                      const u16* __restrict__ WqT,
                                                      const u16* __restrict__ WkT,
                                                      const u16* __restrict__ WvT,
                                                      u16* __restrict__ Qh,
                                                      u16* __restrict__ Kh,
                                                      u16* __restrict__ Vt) {
  __shared__ __align__(16) u16 lA[2][256 * 64];   // 64 KiB
  __shared__ __align__(16) u16 lB[2][256 * 64];   // 64 KiB
  const int z = blockIdx.z;
  const u16* A  = (z == 0) ? Xq : Xkv;
  const u16* Bt = (z == 0) ? WqT : (z == 1) ? WkT : WvT;
  const int Kd = 2048;
  const int tid = threadIdx.x;                    // 0..511
  const int wave = tid >> 6, lane = tid & 63, quad = lane >> 4, l16 = lane & 15;
  const int wm2 = wave >> 2, wn2 = wave & 3;      // 2M x 4N wave grid
  const int bm = blockIdx.x * 256, bn = blockIdx.y * 256;

  // staging geometry: dest 16B-chunk index o16 = q*512 + tid; row = o16>>3,
  // phys slot = o16&7; source column chunk = slot ^ (row&7) (inverse swizzle).
  int srow[4], scol[4];
#pragma unroll
  for (int q = 0; q < 4; q++) {
    int o16 = q * 512 + tid;
    int row = o16 >> 3;
    srow[q] = row;
    scol[q] = ((o16 & 7) ^ (row & 7)) << 3;       // halfword offset in row
  }
  const u16* Ag = A + (size_t)bm * Kd;
  const u16* Bg = Bt + (size_t)bn * Kd;

  // swizzled ds_read offsets: frag rows step by 16, so row&7 == l16&7.
  const int kqs = l16 & 7;
  const int sw0 = (quad ^ kqs) << 3;              // k-slice 0 (cols 0..31)
  const int sw1 = ((4 | quad) ^ kqs) << 3;        // k-slice 1 (cols 32..63)
  const int aBase = (wm2 * 128 + l16) * 64;
  const int bBase = (wn2 * 64 + l16) * 64;

  f32x4 acc[8][4] = {};

  auto STAGE = [&](int t, int nb) {
    const u16* aS = Ag + t * 64;
    const u16* bS = Bg + t * 64;
#pragma unroll
    for (int q = 0; q < 4; q++) {
      glds16(aS + (size_t)srow[q] * Kd + scol[q], &lA[nb][q * 4096 + tid * 8]);
      glds16(bS + (size_t)srow[q] * Kd + scol[q], &lB[nb][q * 4096 + tid * 8]);
    }
  };

  const int NT = Kd >> 6;  // 32 K-tiles
  int cur = 0;
  STAGE(0, 0);
  asm volatile("s_waitcnt vmcnt(0)" ::: "memory");
  __builtin_amdgcn_s_barrier();
  for (int t = 0; t < NT; t++) {
    if (t + 1 < NT) STAGE(t + 1, cur ^ 1);        // in flight across compute(t)
    bf16x8 bfr[4][2];
#pragma unroll
    for (int nf = 0; nf < 4; nf++) {
      bfr[nf][0] = *(const bf16x8*)&lB[cur][bBase + nf * 1024 + sw0];
      bfr[nf][1] = *(const bf16x8*)&lB[cur][bBase + nf * 1024 + sw1];
    }
    __builtin_amdgcn_s_setprio(1);
#pragma unroll
    for (int mf = 0; mf < 8; mf++) {
      bf16x8 a0 = *(const bf16x8*)&lA[cur][aBase + mf * 1024 + sw0];
      bf16x8 a1 = *(const bf16x8*)&lA[cur][aBase + mf * 1024 + sw1];
#pragma unroll
      for (int nf = 0; nf < 4; nf++) {
        acc[mf][nf] = __builtin_amdgcn_mfma_f32_16x16x32_bf16(a0, bfr[nf][0], acc[mf][nf], 0, 0, 0);
        acc[mf][nf] = __builtin_amdgcn_mfma_f32_16x16x32_bf16(a1, bfr[nf][1], acc[mf][nf], 0, 0, 0);
      }
    }
    __builtin_amdgcn_s_setprio(0);
    asm volatile("s_waitcnt vmcnt(0)" ::: "memory");
    __builtin_amdgcn_s_barrier();
    cur ^= 1;
  }

#pragma unroll
  for (int mf = 0; mf < 8; mf++)
#pragma unroll
    for (int nf = 0; nf < 4; nf++)
#pragma unroll
      for (int r = 0; r < 4; r++) {
        int row = bm + wm2 * 128 + mf * 16 + quad * 4 + r;
        int col = bn + wn2 * 64 + nf * 16 + l16;
        float val = acc[mf][nf][r];
        int b = row >> 11, h = col >> 6, d = col & 63;
        if (z == 2) {
          int kpos = row & 2047;
          Vt[(((size_t)(b * 32 + h)) * 64 + d) * 2048 + kpos] = f2bf(val);
        } else {
          u16* O = z ? Kh : Qh;
          int s = row & 2047;
          O[(((size_t)(b * 32 + h)) * 2048 + s) * 64 + d] = f2bf(val);
        }
      }
}

// ---------------- GEMM, C = A * Bt^T (round-0 proven 128^2 body) ----------------
// MODE 1: C f32 [M][N]. Kept for the ctx*Wo output GEMM (512-block grid fills
// the chip better than a 128-block 256^2 grid would).
template<int MODE>
__global__ __launch_bounds__(256, 3) void gemm_bt(const u16* __restrict__ A,
                                                  const u16* __restrict__ Bt,
                                                  void* __restrict__ Cp,
                                                  int M, int N, int Kd) {
  __shared__ __align__(16) u16 lA[128 * 32];
  __shared__ __align__(16) u16 lB[128 * 32];
  const int tid = threadIdx.x;
  const int wave = tid >> 6, lane = tid & 63, quad = lane >> 4, l16 = lane & 15;
  const int bm = blockIdx.x * 128, bn = blockIdx.y * 128;
  const int wm = (wave >> 1) * 64, wn = (wave & 1) * 64;

  const int srow = tid >> 2, scol = (tid & 3) * 8;
  const u16* ag0 = A + (size_t)(bm + srow) * Kd + scol;
  const u16* ag1 = ag0 + (size_t)64 * Kd;
  const u16* bg0 = Bt + (size_t)(bn + srow) * Kd + scol;
  const u16* bg1 = bg0 + (size_t)64 * Kd;
  u16* la0 = &lA[tid * 8];
  u16* la1 = &lA[(tid + 256) * 8];
  u16* lb0 = &lB[tid * 8];
  u16* lb1 = &lB[(tid + 256) * 8];

  f32x4 acc[4][4] = {};
  for (int kk = 0; kk < Kd; kk += 32) {
    glds16(ag0 + kk, la0);
    glds16(ag1 + kk, la1);
    glds16(bg0 + kk, lb0);
    glds16(bg1 + kk, lb1);
    __syncthreads();
    bf16x8 af[4], bfr[4];
#pragma unroll
    for (int t = 0; t < 4; t++) {
      af[t]  = *(const bf16x8*)&lA[(wm + t * 16 + l16) * 32 + quad * 8];
      bfr[t] = *(const bf16x8*)&lB[(wn + t * 16 + l16) * 32 + quad * 8];
    }
#pragma unroll
    for (int mt = 0; mt < 4; mt++)
#pragma unroll
      for (int nt = 0; nt < 4; nt++)
        acc[mt][nt] = __builtin_amdgcn_mfma_f32_16x16x32_bf16(af[mt], bfr[nt], acc[mt][nt], 0, 0, 0);
    __syncthreads();
  }

#pragma unroll
  for (int mt = 0; mt < 4; mt++)
#pragma unroll
    for (int nt = 0; nt < 4; nt++)
#pragma unroll
      for (int r = 0; r < 4; r++) {
        int row = bm + wm + mt * 16 + quad * 4 + r;
        int col = bn + wn + nt * 16 + l16;
        float val = acc[mt][nt][r];
        if (MODE == 0) {
          ((u16*)Cp)[(size_t)row * N + col] = f2bf(val);
        } else {
          ((float*)Cp)[(size_t)row * N + col] = val;
        }
      }
}

// ---------------- flash attention ----------------
// (round-6 verified body, 282 us — stable across occupancy (r1-2), pipelining
// (r3-4) and ILP/launch-bounds (r6) experiments; parked. Occupancy analysis:
// >=8 waves/SIMD needs <=64 unified regs -> always spills. Do not re-attempt.)
__global__ __launch_bounds__(256, 4) void flash2(const u16* __restrict__ Qh,
                                                 const u16* __restrict__ Kh,
                                                 const u16* __restrict__ Vt,
                                                 const float* __restrict__ biasF,
                                                 u16* __restrict__ ctx) {
  __shared__ __align__(16) u16 lP[4][2][16 * 72];
  const int tid = threadIdx.x, wave = tid >> 6, lane = tid & 63;
  const int quad = lane >> 4, l16 = lane & 15;
  const int bid = blockIdx.x;
  const int qt = bid & 15, h = (bid >> 4) & 31, b = bid >> 9;
  const int qbase = qt * 128 + wave * 32;
  const size_t head = (size_t)(b * 32 + h);

  const u16* qp = Qh + (head * 2048 + qbase + l16) * 64 + quad * 8;
  bf16x8 qf[2][2];
  qf[0][0] = *(const bf16x8*)qp;
  qf[0][1] = *(const bf16x8*)(qp + 32);
  qf[1][0] = *(const bf16x8*)(qp + 16 * 64);
  qf[1][1] = *(const bf16x8*)(qp + 16 * 64 + 32);

  const u16* kb = Kh + (head * 2048 + l16) * 64 + quad * 8;
  const u16* vb = Vt + (head * 64 + l16) * 2048 + quad * 8;
  const int qs0 = qbase >> 4;
  const float* bf0 = biasF + (((size_t)b * 128 + qs0) * 128) * 256 + lane * 4;
  const float* bf1 = bf0 + 128 * 256;

  f32x4 acc[2][4] = {};
  float lp[2][4] = {};
  u16* P0 = &lP[wave][0][0];
  u16* P1 = &lP[wave][1][0];

  for (int kt = 0; kt < 32; kt++) {
    const u16* kr = kb + (size_t)kt * 64 * 64;
    const u16* vp = vb + kt * 64;
#pragma unroll
    for (int nt = 0; nt < 4; nt++) {
      bf16x8 k0 = *(const bf16x8*)(kr + nt * 16 * 64);
      bf16x8 k1 = *(const bf16x8*)(kr + nt * 16 * 64 + 32);
      f32x4 z0 = *(const f32x4*)(bf0 + (size_t)(kt * 4 + nt) * 256);
      f32x4 z1 = *(const f32x4*)(bf1 + (size_t)(kt * 4 + nt) * 256);
      z0 = __builtin_amdgcn_mfma_f32_16x16x32_bf16(qf[0][0], k0, z0, 0, 0, 0);
      z0 = __builtin_amdgcn_mfma_f32_16x16x32_bf16(qf[0][1], k1, z0, 0, 0, 0);
      z1 = __builtin_amdgcn_mfma_f32_16x16x32_bf16(qf[1][0], k0, z1, 0, 0, 0);
      z1 = __builtin_amdgcn_mfma_f32_16x16x32_bf16(qf[1][1], k1, z1, 0, 0, 0);
#pragma unroll
      for (int r = 0; r < 4; r++) {
        float e0 = __expf(z0[r]);
        float e1 = __expf(z1[r]);
        lp[0][r] += e0;
        lp[1][r] += e1;
        P0[(quad * 4 + r) * 72 + nt * 16 + l16] = f2bf(e0);
        P1[(quad * 4 + r) * 72 + nt * 16 + l16] = f2bf(e1);
      }
    }
    bf16x8 v0[4], v1[4];
#pragma unroll
    for (int dt = 0; dt < 4; dt++) {
      v0[dt] = *(const bf16x8*)(vp + (size_t)dt * 16 * 2048);
      v1[dt] = *(const bf16x8*)(vp + (size_t)dt * 16 * 2048 + 32);
    }
    bf16x8 pf00 = *(const bf16x8*)&P0[l16 * 72 + quad * 8];
    bf16x8 pf01 = *(const bf16x8*)&P0[l16 * 72 + 32 + quad * 8];
    bf16x8 pf10 = *(const bf16x8*)&P1[l16 * 72 + quad * 8];
    bf16x8 pf11 = *(const bf16x8*)&P1[l16 * 72 + 32 + quad * 8];
#pragma unroll
    for (int dt = 0; dt < 4; dt++) {
      acc[0][dt] = __builtin_amdgcn_mfma_f32_16x16x32_bf16(pf00, v0[dt], acc[0][dt], 0, 0, 0);
      acc[0][dt] = __builtin_amdgcn_mfma_f32_16x16x32_bf16(pf01, v1[dt], acc[0][dt], 0, 0, 0);
      acc[1][dt] = __builtin_amdgcn_mfma_f32_16x16x32_bf16(pf10, v0[dt], acc[1][dt], 0, 0, 0);
      acc[1][dt] = __builtin_amdgcn_mfma_f32_16x16x32_bf16(pf11, v1[dt], acc[1][dt], 0, 0, 0);
    }
  }

  float rv[2][4];
#pragma unroll
  for (int s = 0; s < 2; s++)
#pragma unroll
    for (int r = 0; r < 4; r++) {
      float v = lp[s][r];
      v += __shfl_xor(v, 1);
      v += __shfl_xor(v, 2);
      v += __shfl_xor(v, 4);
      v += __shfl_xor(v, 8);
      rv[s][r] = 1.0f / v;
    }
#pragma unroll
  for (int s = 0; s < 2; s++)
#pragma unroll
    for (int dt = 0; dt < 4; dt++)
#pragma unroll
      for (int r = 0; r < 4; r++) {
        int q = qbase + s * 16 + quad * 4 + r;
        float val = acc[s][dt][r] * rv[s][r];
        ctx[((size_t)(b * 2048 + q)) * 2048 + h * 64 + dt * 16 + l16] = f2bf(val);
      }
}

// ---------------- launch ----------------

extern "C" void kernel_launch(void* const* d_in, const int* in_sizes, int n_in,
                              void* d_out, int out_size, void* d_ws, size_t ws_size,
                              hipStream_t stream) {
  (void)in_sizes; (void)n_in; (void)out_size; (void)ws_size;
  const float* xq   = (const float*)d_in[0];  // [2,2048,2048]
  const float* xkv  = (const float*)d_in[1];  // [2,2048,2048]
  const float* bias = (const float*)d_in[2];  // [2,1,2048,2048]
  const float* wq   = (const float*)d_in[3];  // [2048,32,64]
  const float* wk   = (const float*)d_in[4];
  const float* wv   = (const float*)d_in[5];
  const float* wo   = (const float*)d_in[6];  // [32,64,2048]
  float* out = (float*)d_out;

  u16* w0  = (u16*)d_ws;
  u16* Xq  = w0;                 // 8,388,608 elems (dead after Q/K/V GEMMs)
  u16* Xkv = Xq + 8388608;
  u16* WqT = Xkv + 8388608;      // 4,194,304 each
  u16* WkT = WqT + 4194304;
  u16* WvT = WkT + 4194304;
  u16* WoT = WvT + 4194304;
  u16* Qh  = WoT + 4194304;      // 8,388,608 each
  u16* Kh  = Qh + 8388608;
  u16* Vt  = Kh + 8388608;
  u16* ctx = Vt + 8388608;       // 134 MiB total
  float* biasF = (float*)w0;     // aliases Xq+Xkv (33.5 MB), written after QKV GEMM

  cast_bf16_k<<<8192, 256, 0, stream>>>(xq,  Xq,  2097152);
  cast_bf16_k<<<8192, 256, 0, stream>>>(xkv, Xkv, 2097152);
  dim3 tg(64, 64);
  transpose_cast<<<tg, 256, 0, stream>>>(wq, WqT, 2048, 2048, 0.125f);  // 1/sqrt(64) folded
  transpose_cast<<<tg, 256, 0, stream>>>(wk, WkT, 2048, 2048, 1.0f);
  transpose_cast<<<tg, 256, 0, stream>>>(wv, WvT, 2048, 2048, 1.0f);
  transpose_cast<<<tg, 256, 0, stream>>>(wo, WoT, 2048, 2048, 1.0f);

  dim3 gq(16, 8, 3);  // M/256=16, N/256=8, {Q,K,V}
  gemm_qkv256<<<gq, 512, 0, stream>>>(Xq, Xkv, WqT, WkT, WvT, Qh, Kh, Vt);

  bias_frag<<<8192, 256, 0, stream>>>(bias, biasF);  // after Xq/Xkv are dead

  flash2<<<1024, 256, 0, stream>>>(Qh, Kh, Vt, biasF, ctx);

  dim3 gg(32, 16);  // M/128=32, N/128=16
  gemm_bt<1><<<gg, 256, 0, stream>>>(ctx, WoT, out, 4096, 2048, 2048);
}

// Round 9
// 501.050 us; speedup vs baseline: 1.3451x; 1.3451x over previous
//
#include <hip/hip_runtime.h>
#include <math.h>

typedef unsigned short u16;
typedef __attribute__((ext_vector_type(8))) __bf16 bf16x8;
typedef __attribute__((ext_vector_type(4))) float f32x4;

// RNE float -> bf16
__device__ __forceinline__ u16 f2bf(float f) {
  union { float f; unsigned u; } v; v.f = f;
  unsigned u = v.u;
  u += 0x7fffu + ((u >> 16) & 1u);
  return (u16)(u >> 16);
}

// async global->LDS, 16B per lane. LDS dest must be wave-uniform base + lane*16.
__device__ __forceinline__ void glds16(const void* g, void* l) {
  __builtin_amdgcn_global_load_lds((__attribute__((address_space(1))) void*)(g),
                                   (__attribute__((address_space(3))) void*)(l),
                                   16, 0, 0);
}

// ---------------- stage 0: casts / transposes ----------------

__global__ __launch_bounds__(256) void cast_bf16_k(const float* __restrict__ in,
                                                   u16* __restrict__ out, int n4) {
  int i = blockIdx.x * 256 + threadIdx.x;
  if (i < n4) {
    float4 v = ((const float4*)in)[i];
    u16* o = out + (size_t)i * 4;
    o[0] = f2bf(v.x); o[1] = f2bf(v.y); o[2] = f2bf(v.z); o[3] = f2bf(v.w);
  }
}

// out[c*R + r] = bf16(in[r*C + c] * scale)   (R,C multiples of 32)
__global__ __launch_bounds__(256) void transpose_cast(const float* __restrict__ in,
                                                      u16* __restrict__ out,
                                                      int R, int C, float scale) {
  __shared__ float t[32][33];
  int bx = blockIdx.x * 32;  // col block (in)
  int by = blockIdx.y * 32;  // row block (in)
  int tx = threadIdx.x & 31, ty0 = threadIdx.x >> 5;
  for (int ty = ty0; ty < 32; ty += 8)
    t[ty][tx] = in[(size_t)(by + ty) * C + bx + tx];
  __syncthreads();
  for (int ty = ty0; ty < 32; ty += 8)
    out[(size_t)(bx + ty) * R + by + tx] = f2bf(t[tx][ty] * scale);
}

// bias [b][q][k] f32 -> biasF [b][qs:128][ks:128][lane:64][r:4] f32
// (16x16 MFMA C-fragment order: lane=(quad,l16) holds rows quad*4+r, col l16)
__global__ __launch_bounds__(256) void bias_frag(const float* __restrict__ bias,
                                                 float* __restrict__ biasF) {
  int g = blockIdx.x * 256 + threadIdx.x;   // 2*128*128*64 threads
  int lane = g & 63, ks = (g >> 6) & 127, qs = (g >> 13) & 127, b = g >> 20;
  int quad = lane >> 4, l16 = lane & 15;
  int q = qs * 16 + quad * 4, k = ks * 16 + l16;
  const float* ip = bias + ((size_t)(b * 2048 + q)) * 2048 + k;
  float4 o;
  o.x = ip[0];
  o.y = ip[2048];
  o.z = ip[4096];
  o.w = ip[6144];
  ((float4*)biasF)[g] = o;
}

// ---------------- fused Q/K/V projection GEMM (r6 proven version) ----------------
// One dispatch, gridDim = (32, 16, 3); z selects {A, B, output, layout}:
//   z=0: Qh = Xq  * WqT^T  -> [b][h][s][64]
//   z=1: Kh = Xkv * WkT^T  -> [b][h][s][64]
//   z=2: Vt = Xkv * WvT^T  -> [b][h][d][kpos]
// 128^2 tile, single-buffer LDS, 2x __syncthreads per K-step; co-resident
// block diversity (3 blocks/CU) is the latency-hiding mechanism. GEMM
// structure experiments r3/r4 (prefetch pipelines) and r7/r8 (256^2 2-phase,
// ~258us vs this 230us: 1 block/CU + 1.5-generation grid tail) all lost to
// this. Do not revisit without a new mechanism.
__global__ __launch_bounds__(256, 3) void gemm_qkv(const u16* __restrict__ Xq,
                                                   const u16* __restrict__ Xkv,
                                                   const u16* __restrict__ WqT,
                                                   const u16* __restrict__ WkT,
                                                   const u16* __restrict__ WvT,
                                                   u16* __restrict__ Qh,
                                                   u16* __restrict__ Kh,
                                                   u16* __restrict__ Vt) {
  __shared__ __align__(16) u16 lA[128 * 32];
  __shared__ __align__(16) u16 lB[128 * 32];
  const int z = blockIdx.z;
  const u16* A  = (z == 0) ? Xq : Xkv;
  const u16* Bt = (z == 0) ? WqT : (z == 1) ? WkT : WvT;
  const int Kd = 2048;
  const int tid = threadIdx.x;
  const int wave = tid >> 6, lane = tid & 63, quad = lane >> 4, l16 = lane & 15;
  const int bm = blockIdx.x * 128, bn = blockIdx.y * 128;
  const int wm = (wave >> 1) * 64, wn = (wave & 1) * 64;

  const int srow = tid >> 2, scol = (tid & 3) * 8;
  const u16* ag0 = A + (size_t)(bm + srow) * Kd + scol;
  const u16* ag1 = ag0 + (size_t)64 * Kd;
  const u16* bg0 = Bt + (size_t)(bn + srow) * Kd + scol;
  const u16* bg1 = bg0 + (size_t)64 * Kd;
  u16* la0 = &lA[tid * 8];
  u16* la1 = &lA[(tid + 256) * 8];
  u16* lb0 = &lB[tid * 8];
  u16* lb1 = &lB[(tid + 256) * 8];

  f32x4 acc[4][4] = {};
  for (int kk = 0; kk < Kd; kk += 32) {
    glds16(ag0 + kk, la0);
    glds16(ag1 + kk, la1);
    glds16(bg0 + kk, lb0);
    glds16(bg1 + kk, lb1);
    __syncthreads();
    bf16x8 af[4], bfr[4];
#pragma unroll
    for (int t = 0; t < 4; t++) {
      af[t]  = *(const bf16x8*)&lA[(wm + t * 16 + l16) * 32 + quad * 8];
      bfr[t] = *(const bf16x8*)&lB[(wn + t * 16 + l16) * 32 + quad * 8];
    }
#pragma unroll
    for (int mt = 0; mt < 4; mt++)
#pragma unroll
      for (int nt = 0; nt < 4; nt++)
        acc[mt][nt] = __builtin_amdgcn_mfma_f32_16x16x32_bf16(af[mt], bfr[nt], acc[mt][nt], 0, 0, 0);
    __syncthreads();
  }

#pragma unroll
  for (int mt = 0; mt < 4; mt++)
#pragma unroll
    for (int nt = 0; nt < 4; nt++)
#pragma unroll
      for (int r = 0; r < 4; r++) {
        int row = bm + wm + mt * 16 + quad * 4 + r;
        int col = bn + wn + nt * 16 + l16;
        float val = acc[mt][nt][r];
        int b = row >> 11;
        int h = col >> 6, d = col & 63;
        if (z == 2) {
          int kpos = row & 2047;
          Vt[(((size_t)(b * 32 + h)) * 64 + d) * 2048 + kpos] = f2bf(val);
        } else {
          u16* O = z ? Kh : Qh;
          int s = row & 2047;
          O[(((size_t)(b * 32 + h)) * 2048 + s) * 64 + d] = f2bf(val);
        }
      }
}

// ---------------- GEMM, C = A * Bt^T (round-0 proven 128^2 body) ----------------
// MODE 1: C f32 [M][N]. Used for the ctx*Wo output GEMM.
template<int MODE>
__global__ __launch_bounds__(256, 3) void gemm_bt(const u16* __restrict__ A,
                                                  const u16* __restrict__ Bt,
                                                  void* __restrict__ Cp,
                                                  int M, int N, int Kd) {
  __shared__ __align__(16) u16 lA[128 * 32];
  __shared__ __align__(16) u16 lB[128 * 32];
  const int tid = threadIdx.x;
  const int wave = tid >> 6, lane = tid & 63, quad = lane >> 4, l16 = lane & 15;
  const int bm = blockIdx.x * 128, bn = blockIdx.y * 128;
  const int wm = (wave >> 1) * 64, wn = (wave & 1) * 64;

  const int srow = tid >> 2, scol = (tid & 3) * 8;
  const u16* ag0 = A + (size_t)(bm + srow) * Kd + scol;
  const u16* ag1 = ag0 + (size_t)64 * Kd;
  const u16* bg0 = Bt + (size_t)(bn + srow) * Kd + scol;
  const u16* bg1 = bg0 + (size_t)64 * Kd;
  u16* la0 = &lA[tid * 8];
  u16* la1 = &lA[(tid + 256) * 8];
  u16* lb0 = &lB[tid * 8];
  u16* lb1 = &lB[(tid + 256) * 8];

  f32x4 acc[4][4] = {};
  for (int kk = 0; kk < Kd; kk += 32) {
    glds16(ag0 + kk, la0);
    glds16(ag1 + kk, la1);
    glds16(bg0 + kk, lb0);
    glds16(bg1 + kk, lb1);
    __syncthreads();
    bf16x8 af[4], bfr[4];
#pragma unroll
    for (int t = 0; t < 4; t++) {
      af[t]  = *(const bf16x8*)&lA[(wm + t * 16 + l16) * 32 + quad * 8];
      bfr[t] = *(const bf16x8*)&lB[(wn + t * 16 + l16) * 32 + quad * 8];
    }
#pragma unroll
    for (int mt = 0; mt < 4; mt++)
#pragma unroll
      for (int nt = 0; nt < 4; nt++)
        acc[mt][nt] = __builtin_amdgcn_mfma_f32_16x16x32_bf16(af[mt], bfr[nt], acc[mt][nt], 0, 0, 0);
    __syncthreads();
  }

#pragma unroll
  for (int mt = 0; mt < 4; mt++)
#pragma unroll
    for (int nt = 0; nt < 4; nt++)
#pragma unroll
      for (int r = 0; r < 4; r++) {
        int row = bm + wm + mt * 16 + quad * 4 + r;
        int col = bn + wn + nt * 16 + l16;
        float val = acc[mt][nt][r];
        if (MODE == 0) {
          ((u16*)Cp)[(size_t)row * N + col] = f2bf(val);
        } else {
          ((float*)Cp)[(size_t)row * N + col] = val;
        }
      }
}

// ---------------- flash attention, v3: block-shared K/V in LDS ----------------
// Round-9 theory: flash2 was VMEM-issue bound — 16 resident waves/CU each
// independently streaming K and V issued 384 vector-loads/CU per kt (24/wave)
// into one texture path + ~33%-loaded L2, giving ~21K cy/kt stalls while
// every pipe idled (Mfma 10%, VALU 18%, HBM 8%).
// Fix: K-tile [64k][64d] and V-tile [64d][64k] staged to LDS ONCE per block
// per kt (16 glds16 total = 4/wave), XOR-swizzled (st pattern verified
// correct in r8's QKV256): linear glds dest + inverse-swizzled global source
// (col chunk ^= row&7) + swizzled ds_read (chunk ^= l16&7; frag rows step 16
// so row&7==l16&7 is static). Single-buffered, 2 __syncthreads per kt —
// the r0-GEMM proven pattern; 4 blocks/CU co-residency hides the drain.
// Per-CU VMEM wave-loads per kt: 384 -> 192 (bias stays per-wave, f32).
// Q frags, bias path, P roundtrip, softmax, epilogue: identical to r6.
__global__ __launch_bounds__(256, 4) void flash3(const u16* __restrict__ Qh,
                                                 const u16* __restrict__ Kh,
                                                 const u16* __restrict__ Vt,
                                                 const float* __restrict__ biasF,
                                                 u16* __restrict__ ctx) {
  __shared__ __align__(16) u16 lK[64 * 64];       // 8 KiB, swizzled
  __shared__ __align__(16) u16 lV[64 * 64];       // 8 KiB, swizzled
  __shared__ __align__(16) u16 lP[4][2][16 * 72]; // 18 KiB, per-wave P bufs
  const int tid = threadIdx.x, wave = tid >> 6, lane = tid & 63;
  const int quad = lane >> 4, l16 = lane & 15;
  const int bid = blockIdx.x;
  const int qt = bid & 15, h = (bid >> 4) & 31, b = bid >> 9;
  const int qbase = qt * 128 + wave * 32;
  const size_t head = (size_t)(b * 32 + h);

  const u16* qp = Qh + (head * 2048 + qbase + l16) * 64 + quad * 8;
  bf16x8 qf[2][2];
  qf[0][0] = *(const bf16x8*)qp;
  qf[0][1] = *(const bf16x8*)(qp + 32);
  qf[1][0] = *(const bf16x8*)(qp + 16 * 64);
  qf[1][1] = *(const bf16x8*)(qp + 16 * 64 + 32);

  // staging geometry: 512 16B-chunks per tile; chunk o = q*256 + tid;
  // row = o>>3 (0..63); logical col chunk = (o&7) ^ (row&7)  (inverse swizzle)
  int srow[2], scol[2];
#pragma unroll
  for (int q = 0; q < 2; q++) {
    int o = q * 256 + tid;
    srow[q] = o >> 3;
    scol[q] = ((o & 7) ^ (srow[q] & 7)) << 3;   // halfword offset in row
  }
  const u16* Kbase = Kh + head * 2048 * 64;     // [s][64]
  const u16* Vbase = Vt + head * 64 * 2048;     // [d][2048]

  // swizzled ds_read chunk offsets (row&7 == l16&7 for all frag rows)
  const int s7 = l16 & 7;
  const int swA = (quad ^ s7) << 3;             // cols 0..31 half
  const int swB = ((quad | 4) ^ s7) << 3;       // cols 32..63 half

  const int qs0 = qbase >> 4;
  const float* bf0 = biasF + (((size_t)b * 128 + qs0) * 128) * 256 + lane * 4;
  const float* bf1 = bf0 + 128 * 256;

  f32x4 acc[2][4] = {};
  float lp[2][4] = {};
  u16* P0 = &lP[wave][0][0];
  u16* P1 = &lP[wave][1][0];

  for (int kt = 0; kt < 32; kt++) {
    // ---- stage K,V tiles (4 glds16 per lane for the whole block) ----
#pragma unroll
    for (int q = 0; q < 2; q++)
      glds16(Kbase + (size_t)(kt * 64 + srow[q]) * 64 + scol[q],
             &lK[(q * 256 + tid) * 8]);
#pragma unroll
    for (int q = 0; q < 2; q++)
      glds16(Vbase + (size_t)srow[q] * 2048 + kt * 64 + scol[q],
             &lV[(q * 256 + tid) * 8]);
    __syncthreads();  // vmcnt(0)+lgkmcnt(0) drain: tiles ready for all waves

    // ---- QK^T + bias, exp, P store (per-wave buffers, unchanged math) ----
#pragma unroll
    for (int nt = 0; nt < 4; nt++) {
      int krow = nt * 16 + l16;
      bf16x8 k0 = *(const bf16x8*)&lK[krow * 64 + swA];
      bf16x8 k1 = *(const bf16x8*)&lK[krow * 64 + swB];
      f32x4 z0 = *(const f32x4*)(bf0 + (size_t)(kt * 4 + nt) * 256);
      f32x4 z1 = *(const f32x4*)(bf1 + (size_t)(kt * 4 + nt) * 256);
      z0 = __builtin_amdgcn_mfma_f32_16x16x32_bf16(qf[0][0], k0, z0, 0, 0, 0);
      z0 = __builtin_amdgcn_mfma_f32_16x16x32_bf16(qf[0][1], k1, z0, 0, 0, 0);
      z1 = __builtin_amdgcn_mfma_f32_16x16x32_bf16(qf[1][0], k0, z1, 0, 0, 0);
      z1 = __builtin_amdgcn_mfma_f32_16x16x32_bf16(qf[1][1], k1, z1, 0, 0, 0);
#pragma unroll
      for (int r = 0; r < 4; r++) {
        float e0 = __expf(z0[r]);
        float e1 = __expf(z1[r]);
        lp[0][r] += e0;
        lp[1][r] += e1;
        P0[(quad * 4 + r) * 72 + nt * 16 + l16] = f2bf(e0);
        P1[(quad * 4 + r) * 72 + nt * 16 + l16] = f2bf(e1);
      }
    }
    // ---- P read-back + PV from LDS V tile ----
    bf16x8 pf00 = *(const bf16x8*)&P0[l16 * 72 + quad * 8];
    bf16x8 pf01 = *(const bf16x8*)&P0[l16 * 72 + 32 + quad * 8];
    bf16x8 pf10 = *(const bf16x8*)&P1[l16 * 72 + quad * 8];
    bf16x8 pf11 = *(const bf16x8*)&P1[l16 * 72 + 32 + quad * 8];
#pragma unroll
    for (int dt = 0; dt < 4; dt++) {
      int vrow = dt * 16 + l16;
      bf16x8 v0 = *(const bf16x8*)&lV[vrow * 64 + swA];
      bf16x8 v1 = *(const bf16x8*)&lV[vrow * 64 + swB];
      acc[0][dt] = __builtin_amdgcn_mfma_f32_16x16x32_bf16(pf00, v0, acc[0][dt], 0, 0, 0);
      acc[0][dt] = __builtin_amdgcn_mfma_f32_16x16x32_bf16(pf01, v1, acc[0][dt], 0, 0, 0);
      acc[1][dt] = __builtin_amdgcn_mfma_f32_16x16x32_bf16(pf10, v0, acc[1][dt], 0, 0, 0);
      acc[1][dt] = __builtin_amdgcn_mfma_f32_16x16x32_bf16(pf11, v1, acc[1][dt], 0, 0, 0);
    }
    __syncthreads();  // all reads of lK/lV retired before next stage
  }

  float rv[2][4];
#pragma unroll
  for (int s = 0; s < 2; s++)
#pragma unroll
    for (int r = 0; r < 4; r++) {
      float v = lp[s][r];
      v += __shfl_xor(v, 1);
      v += __shfl_xor(v, 2);
      v += __shfl_xor(v, 4);
      v += __shfl_xor(v, 8);
      rv[s][r] = 1.0f / v;
    }
#pragma unroll
  for (int s = 0; s < 2; s++)
#pragma unroll
    for (int dt = 0; dt < 4; dt++)
#pragma unroll
      for (int r = 0; r < 4; r++) {
        int q = qbase + s * 16 + quad * 4 + r;
        float val = acc[s][dt][r] * rv[s][r];
        ctx[((size_t)(b * 2048 + q)) * 2048 + h * 64 + dt * 16 + l16] = f2bf(val);
      }
}

// ---------------- launch ----------------

extern "C" void kernel_launch(void* const* d_in, const int* in_sizes, int n_in,
                              void* d_out, int out_size, void* d_ws, size_t ws_size,
                              hipStream_t stream) {
  (void)in_sizes; (void)n_in; (void)out_size; (void)ws_size;
  const float* xq   = (const float*)d_in[0];  // [2,2048,2048]
  const float* xkv  = (const float*)d_in[1];  // [2,2048,2048]
  const float* bias = (const float*)d_in[2];  // [2,1,2048,2048]
  const float* wq   = (const float*)d_in[3];  // [2048,32,64]
  const float* wk   = (const float*)d_in[4];
  const float* wv   = (const float*)d_in[5];
  const float* wo   = (const float*)d_in[6];  // [32,64,2048]
  float* out = (float*)d_out;

  u16* w0  = (u16*)d_ws;
  u16* Xq  = w0;                 // 8,388,608 elems (dead after Q/K/V GEMMs)
  u16* Xkv = Xq + 8388608;
  u16* WqT = Xkv + 8388608;      // 4,194,304 each
  u16* WkT = WqT + 4194304;
  u16* WvT = WkT + 4194304;
  u16* WoT = WvT + 4194304;
  u16* Qh  = WoT + 4194304;      // 8,388,608 each
  u16* Kh  = Qh + 8388608;
  u16* Vt  = Kh + 8388608;
  u16* ctx = Vt + 8388608;       // 134 MiB total
  float* biasF = (float*)w0;     // aliases Xq+Xkv (33.5 MB), written after QKV GEMM

  cast_bf16_k<<<8192, 256, 0, stream>>>(xq,  Xq,  2097152);
  cast_bf16_k<<<8192, 256, 0, stream>>>(xkv, Xkv, 2097152);
  dim3 tg(64, 64);
  transpose_cast<<<tg, 256, 0, stream>>>(wq, WqT, 2048, 2048, 0.125f);  // 1/sqrt(64) folded
  transpose_cast<<<tg, 256, 0, stream>>>(wk, WkT, 2048, 2048, 1.0f);
  transpose_cast<<<tg, 256, 0, stream>>>(wv, WvT, 2048, 2048, 1.0f);
  transpose_cast<<<tg, 256, 0, stream>>>(wo, WoT, 2048, 2048, 1.0f);

  dim3 gq(32, 16, 3);  // M/128=32, N/128=16, {Q,K,V}
  gemm_qkv<<<gq, 256, 0, stream>>>(Xq, Xkv, WqT, WkT, WvT, Qh, Kh, Vt);

  bias_frag<<<8192, 256, 0, stream>>>(bias, biasF);  // after Xq/Xkv are dead

  flash3<<<1024, 256, 0, stream>>>(Qh, Kh, Vt, biasF, ctx);

  dim3 gg(32, 16);  // M/128=32, N/128=16
  gemm_bt<1><<<gg, 256, 0, stream>>>(ctx, WoT, out, 4096, 2048, 2048);
}